// Round 1
// baseline (51.250 us; speedup 1.0000x reference)
//
#include <hip/hip_runtime.h>

// Spatial correlation sampler with max over 9x9 offsets.
// Key identity: out = f1 >= 0 ? f1 * windowMax(f2pad) : f1 * windowMin(f2pad),
// computed as a separable 9-wide max/min (Gil-Werman-style log trees),
// one (b,c) plane of 38x68 per 256-thread block.

#define BB 16
#define CC 512
#define HH 38
#define WW 68
#define PLANE (HH * WW)   // 2584
#define S2S 84            // LDS stride for padded f2 row: 4 zero | 68 data | 8 zero (+4 slack)
#define HMROWS 48         // padded rows for hm: 4 zero | 38 data | 6 zero

__global__ __launch_bounds__(256) void corr_winmax_kernel(
    const float* __restrict__ f1, const float* __restrict__ f2,
    float* __restrict__ out)
{
    __shared__ float  s2[HH * S2S];       // 12768 B, padded cols
    __shared__ float2 hm[HMROWS * WW];    // 26112 B, .x = row max, .y = row min, padded rows

    const int t = threadIdx.x;
    const int base = blockIdx.x * PLANE;  // blockIdx.x in [0, B*C)

    // ---- phase 0: zero pads + stage f2 plane into LDS (float4) ----
    for (int i = t; i < 456; i += 256) {            // 38 rows x 12 pad cols
        int r = i / 12, j = i % 12;
        int col = (j < 4) ? j : (j + 68);           // cols [0,4) and [72,80)
        s2[r * S2S + col] = 0.0f;
    }
    for (int i = t; i < 680; i += 256) {            // 10 pad rows x 68 cols
        int rr = i / 68, col = i % 68;
        int row = (rr < 4) ? rr : (rr + 38);        // rows [0,4) and [42,48)
        hm[row * WW + col] = make_float2(0.0f, 0.0f);
    }
    for (int j = t; j < 646; j += 256) {            // 38 rows x 17 float4
        int r = j / 17, q = j % 17;
        float4 v = *reinterpret_cast<const float4*>(f2 + base + r * WW + q * 4);
        *reinterpret_cast<float4*>(&s2[r * S2S + 4 + q * 4]) = v;  // 16B-aligned
    }
    __syncthreads();

    // ---- phase 1: horizontal 9-window max/min, 9-wide output segments ----
    // job j: row r = j>>3 (38 rows), segment seg = j&7, outputs real cols [c0, c0+9)
    for (int j = t; j < 304; j += 256) {
        int r = j >> 3, seg = j & 7, c0 = seg * 9;
        float v[17];
        #pragma unroll
        for (int i = 0; i < 17; ++i) v[i] = s2[r * S2S + c0 + i]; // padded cols [c0, c0+16]
        float ax[16], an[16];
        #pragma unroll
        for (int i = 0; i < 16; ++i) { ax[i] = fmaxf(v[i], v[i+1]); an[i] = fminf(v[i], v[i+1]); }
        float bx[14], bn[14];
        #pragma unroll
        for (int i = 0; i < 14; ++i) { bx[i] = fmaxf(ax[i], ax[i+2]); bn[i] = fminf(an[i], an[i+2]); }
        float cx[10], cn[10];
        #pragma unroll
        for (int i = 0; i < 10; ++i) { cx[i] = fmaxf(bx[i], bx[i+4]); cn[i] = fminf(bn[i], bn[i+4]); }
        #pragma unroll
        for (int k = 0; k < 9; ++k) {               // window = v[k..k+8]
            int col = c0 + k;
            if (col < WW)
                hm[(r + 4) * WW + col] =
                    make_float2(fmaxf(cx[k], v[k+8]), fminf(cn[k], v[k+8]));
        }
    }
    __syncthreads();

    // ---- phase 2: vertical 9-window max/min + sign-select multiply + store ----
    // job j: col = j%68, vertical segment vs = j/68, outputs real rows [h0, h0+10)
    for (int j = t; j < 272; j += 256) {
        int col = j % 68, vs = j / 68, h0 = vs * 10;
        float2 u[18];
        #pragma unroll
        for (int i = 0; i < 18; ++i) u[i] = hm[(h0 + i) * WW + col]; // padded rows [h0, h0+17]
        float ax[17], an[17];
        #pragma unroll
        for (int i = 0; i < 17; ++i) { ax[i] = fmaxf(u[i].x, u[i+1].x); an[i] = fminf(u[i].y, u[i+1].y); }
        float bx[15], bn[15];
        #pragma unroll
        for (int i = 0; i < 15; ++i) { bx[i] = fmaxf(ax[i], ax[i+2]); bn[i] = fminf(an[i], an[i+2]); }
        float cx[11], cn[11];
        #pragma unroll
        for (int i = 0; i < 11; ++i) { cx[i] = fmaxf(bx[i], bx[i+4]); cn[i] = fminf(bn[i], bn[i+4]); }
        #pragma unroll
        for (int k = 0; k < 10; ++k) {              // window = u[k..k+8]
            int h = h0 + k;
            if (h < HH) {
                float mx = fmaxf(cx[k], u[k+8].x);
                float mn = fminf(cn[k], u[k+8].y);
                int idx = base + h * WW + col;
                float a = f1[idx];
                out[idx] = a * (a >= 0.0f ? mx : mn);
            }
        }
    }
}

extern "C" void kernel_launch(void* const* d_in, const int* in_sizes, int n_in,
                              void* d_out, int out_size, void* d_ws, size_t ws_size,
                              hipStream_t stream) {
    const float* f1 = (const float*)d_in[0];
    const float* f2 = (const float*)d_in[1];
    float* out = (float*)d_out;
    corr_winmax_kernel<<<dim3(BB * CC), dim3(256), 0, stream>>>(f1, f2, out);
}